// Round 2
// baseline (6683.926 us; speedup 1.0000x reference)
//
#include <hip/hip_runtime.h>
#include <hip/hip_bf16.h>

// ---------------------------------------------------------------------------
// MA_LSTM on MI355X (gfx950). fp32 inputs/outputs (per reference), bf16 MFMA
// internally, fp32 state. Per step t:
//   z = x_t@Wk + h@Wr + c@Wc + bias   (MFMA 16x16x32 bf16, hi/lo split h,c)
//   gates: cumsoftmax(up l2r / down r2l), row dots, O=[O1|O2|O3]
//   f = sigmoid(O@agg); c' = f*c + (1-f)*tanh(z4); h' = z3*tanh(c')
// ---------------------------------------------------------------------------

typedef short  bf16x8 __attribute__((ext_vector_type(8)));
typedef float  f32x4  __attribute__((ext_vector_type(4)));
typedef __hip_bfloat16 bf16;

#define U 1024
#define BATCH 64
#define TSTEPS 128
#define DIM 256
#define N5 5120
#define K2 2048   // h(1024) + c(1024)

// ---- workspace layout (bytes) ----
#define OFF_WRC   0u                       // bf16 [5120][2048]  (Wr^T | Wc^T)
#define OFF_KT    20971520u                // bf16 [5120][256]   kernel^T
#define OFF_AGGT  23592960u                // bf16 [1024][3072]  aggregation^T
#define OFF_XBF   29884416u                // bf16 [64][128][256] x in bf16
#define OFF_Z     34078720u                // f32  [64][5120]
#define OFF_ABUF  35389440u                // bf16 [4][64][1024] h_hi,h_lo,c_hi,c_lo
#define OFF_C32   35913728u                // f32  [64][1024]
#define OFF_OBUF  36175872u                // bf16 [64][3072]
#define OFF_SCAL  36569088u                // f32  [8]

// ---------------------------------------------------------------------------
// x: fp32 -> bf16, 4 elements/thread
__global__ __launch_bounds__(256) void k_xconv(const float* __restrict__ in,
                                               bf16* __restrict__ o, int n4) {
    const int i = blockIdx.x * 256 + threadIdx.x;
    if (i < n4) {
        const float4 v = ((const float4*)in)[i];
        bf16 tmp[4] = {__float2bfloat16(v.x), __float2bfloat16(v.y),
                       __float2bfloat16(v.z), __float2bfloat16(v.w)};
        ((uint2*)o)[i] = *(const uint2*)tmp;
    }
}

// ---------------------------------------------------------------------------
// tiled transpose + fp32->bf16: out[c*out_stride + out_off + r] = bf16(in[r*C+c])
// all dims multiples of 64.
__global__ __launch_bounds__(256) void k_transpose(const float* __restrict__ in,
                                                   bf16* __restrict__ out,
                                                   int C, int out_stride, int out_off) {
    __shared__ bf16 tile[64][65];
    const int tc = blockIdx.x * 64, tr = blockIdx.y * 64;
    const int tx = threadIdx.x & 63, ty0 = threadIdx.x >> 6;
#pragma unroll
    for (int i = 0; i < 64; i += 4)
        tile[ty0 + i][tx] = __float2bfloat16(in[(tr + ty0 + i) * C + tc + tx]);
    __syncthreads();
#pragma unroll
    for (int i = 0; i < 64; i += 4)
        out[(tc + ty0 + i) * out_stride + out_off + tr + tx] = tile[tx][ty0 + i];
}

// ---------------------------------------------------------------------------
struct AttPtrs { const float* p[12]; };

__global__ __launch_bounds__(256) void k_scal(AttPtrs ap, float* __restrict__ scal) {
    __shared__ float red[256];
    const int tid = threadIdx.x;
    for (int q = 0; q < 6; ++q) {
        const float* l = ap.p[2 * q];
        const float* r = ap.p[2 * q + 1];
        float s = 0.f;
        for (int i = tid; i < 1024; i += 256)
            s += l[i] * r[i];
        red[tid] = s; __syncthreads();
        for (int o = 128; o > 0; o >>= 1) {
            if (tid < o) red[tid] += red[tid + o];
            __syncthreads();
        }
        if (tid == 0) scal[q] = red[0];
        __syncthreads();
    }
}

// ---------------------------------------------------------------------------
// z-GEMM: z[b][n] = sum_d x[b][t][d]*kt[n][d] + sum_k (hhi+hlo)[b][k]*wrct[n][k]
//                 + sum_k (chi+clo)[b][k]*wrct[n][1024+k] + bias[n]
// grid 160 blocks (n-tile 32), 256 thr = 4 waves, k-split across waves.
__global__ __launch_bounds__(256) void k_zgemm(const bf16* __restrict__ x,
                                               const bf16* __restrict__ kt,
                                               const bf16* __restrict__ wrct,
                                               const bf16* __restrict__ abuf,
                                               const float* __restrict__ bias,
                                               float* __restrict__ z, int t) {
    __shared__ float lacc[4][8][64][4];
    const int tid = threadIdx.x;
    const int w = tid >> 6, lane = tid & 63;
    const int n0 = blockIdx.x * 32;
    const int q = lane >> 4, ml = lane & 15;
    const int nA = n0 + ml, nB = n0 + 16 + ml;

    f32x4 acc[8];
#pragma unroll
    for (int i = 0; i < 8; ++i) acc[i] = (f32x4){0.f, 0.f, 0.f, 0.f};

    for (int i = 0; i < 18; ++i) {
        const int p = i * 4 + w;                 // wave-uniform
        bf16x8 a0[4], a1[4], b[2];
        bool dual;
        if (p < 8) {                              // x @ kernel
            const int kb = p * 32 + q * 8;
#pragma unroll
            for (int mi = 0; mi < 4; ++mi)
                a0[mi] = *(const bf16x8*)(x + (((mi * 16 + ml) * TSTEPS + t) * DIM + kb));
            b[0] = *(const bf16x8*)(kt + nA * DIM + kb);
            b[1] = *(const bf16x8*)(kt + nB * DIM + kb);
            dual = false;
        } else {                                  // h or c @ weights (hi/lo)
            const int isC = (p >= 40);
            const int kb = (p - (isC ? 40 : 8)) * 32 + q * 8;
            const bf16* hiP = abuf + (isC ? 2 : 0) * 65536;
            const bf16* loP = abuf + (isC ? 3 : 1) * 65536;
#pragma unroll
            for (int mi = 0; mi < 4; ++mi) {
                const int m = mi * 16 + ml;
                a0[mi] = *(const bf16x8*)(hiP + m * U + kb);
                a1[mi] = *(const bf16x8*)(loP + m * U + kb);
            }
            const int kcol = (isC ? 1024 : 0) + kb;
            b[0] = *(const bf16x8*)(wrct + nA * K2 + kcol);
            b[1] = *(const bf16x8*)(wrct + nB * K2 + kcol);
            dual = true;
        }
#pragma unroll
        for (int ni = 0; ni < 2; ++ni)
#pragma unroll
            for (int mi = 0; mi < 4; ++mi) {
                acc[mi * 2 + ni] = __builtin_amdgcn_mfma_f32_16x16x32_bf16(
                    a0[mi], b[ni], acc[mi * 2 + ni], 0, 0, 0);
                if (dual)
                    acc[mi * 2 + ni] = __builtin_amdgcn_mfma_f32_16x16x32_bf16(
                        a1[mi], b[ni], acc[mi * 2 + ni], 0, 0, 0);
            }
    }

#pragma unroll
    for (int tile = 0; tile < 8; ++tile)
        *(f32x4*)&lacc[w][tile][lane][0] = acc[tile];
    __syncthreads();

    for (int idx = tid; idx < 2048; idx += 256) {
        const int tile = idx >> 8, rem = idx & 255, ln = rem >> 2, r = rem & 3;
        float v = lacc[0][tile][ln][r] + lacc[1][tile][ln][r]
                + lacc[2][tile][ln][r] + lacc[3][tile][ln][r];
        const int mi = tile >> 1, ni = tile & 1;
        const int row = mi * 16 + (ln >> 4) * 4 + r;
        const int col = n0 + ni * 16 + (ln & 15);
        z[row * N5 + col] = v + bias[col];
    }
}

// ---------------------------------------------------------------------------
// block collectives (256 threads = 4 waves)
__device__ __forceinline__ float wave_sum(float v) {
#pragma unroll
    for (int o = 32; o > 0; o >>= 1) v += __shfl_xor(v, o, 64);
    return v;
}
__device__ __forceinline__ float wave_max(float v) {
#pragma unroll
    for (int o = 32; o > 0; o >>= 1) v = fmaxf(v, __shfl_xor(v, o, 64));
    return v;
}
__device__ __forceinline__ float wave_scan(float v, int lane) {
#pragma unroll
    for (int o = 1; o < 64; o <<= 1) {
        float n = __shfl_up(v, o, 64);
        if (lane >= o) v += n;
    }
    return v;
}
__device__ __forceinline__ float block_sum(float v, float* sm4, int w, int lane) {
    float s = wave_sum(v);
    if (lane == 0) sm4[w] = s;
    __syncthreads();
    float r = sm4[0] + sm4[1] + sm4[2] + sm4[3];
    __syncthreads();
    return r;
}
__device__ __forceinline__ float block_max(float v, float* sm4, int w, int lane) {
    float s = wave_max(v);
    if (lane == 0) sm4[w] = s;
    __syncthreads();
    float r = fmaxf(fmaxf(sm4[0], sm4[1]), fmaxf(sm4[2], sm4[3]));
    __syncthreads();
    return r;
}
// inclusive scan across block; *total gets the full sum
__device__ __forceinline__ float block_scan(float v, float* sm4, int w, int lane, float* total) {
    float ws = wave_scan(v, lane);
    if (lane == 63) sm4[w] = ws;
    __syncthreads();
    float base = 0.f;
    if (w > 0) base += sm4[0];
    if (w > 1) base += sm4[1];
    if (w > 2) base += sm4[2];
    *total = sm4[0] + sm4[1] + sm4[2] + sm4[3];
    __syncthreads();
    return base + ws;
}
__device__ __forceinline__ float sigm(float x) { return 1.f / (1.f + __expf(-x)); }

// one block per batch row b. thread handles j = tid*4 .. tid*4+3
__global__ __launch_bounds__(256) void k_gates(const float* __restrict__ z,
                                               const float* __restrict__ scal,
                                               bf16* __restrict__ obuf) {
    __shared__ float sm4[4];
    const int b = blockIdx.x, tid = threadIdx.x;
    const int w = tid >> 6, lane = tid & 63;
    const float* zr = z + b * N5;

    const float4 zu = ((const float4*)zr)[tid];
    const float4 zd = ((const float4*)(zr + U))[tid];
    const float4 zn = ((const float4*)(zr + 2 * U))[tid];

    // ---- up = cumsum_l2r(softmax(zu)) ----
    float mup = block_max(fmaxf(fmaxf(zu.x, zu.y), fmaxf(zu.z, zu.w)), sm4, w, lane);
    const float e0 = __expf(zu.x - mup), e1 = __expf(zu.y - mup),
                e2 = __expf(zu.z - mup), e3 = __expf(zu.w - mup);
    float totu;
    float inclu = block_scan(e0 + e1 + e2 + e3, sm4, w, lane, &totu);
    const float exclu = inclu - (e0 + e1 + e2 + e3);
    const float inv_u = 1.f / totu;
    const float u0 = (exclu + e0) * inv_u;
    const float u1 = (exclu + e0 + e1) * inv_u;
    const float u2 = (exclu + e0 + e1 + e2) * inv_u;
    const float u3 = (exclu + e0 + e1 + e2 + e3) * inv_u;

    // ---- down = cumsum_r2l(softmax(zd)) (inclusive suffix) ----
    float mdn = block_max(fmaxf(fmaxf(zd.x, zd.y), fmaxf(zd.z, zd.w)), sm4, w, lane);
    const float f0 = __expf(zd.x - mdn), f1 = __expf(zd.y - mdn),
                f2 = __expf(zd.z - mdn), f3 = __expf(zd.w - mdn);
    float totd;
    float incld = block_scan(f0 + f1 + f2 + f3, sm4, w, lane, &totd);
    const float excld = incld - (f0 + f1 + f2 + f3);
    const float inv_d = 1.f / totd;
    const float d0 = (totd - excld) * inv_d;
    const float d1 = (totd - excld - f0) * inv_d;
    const float d2 = (totd - excld - f0 - f1) * inv_d;
    const float d3 = (totd - excld - f0 - f1 - f2) * inv_d;

    // ---- row dots ----
    const float du = block_sum(d0 * u0 + d1 * u1 + d2 * u2 + d3 * u3, sm4, w, lane);
    const float ru = block_sum(zn.x * u0 + zn.y * u1 + zn.z * u2 + zn.w * u3, sm4, w, lane);
    const float dr = block_sum(d0 * zn.x + d1 * zn.y + d2 * zn.z + d3 * zn.w, sm4, w, lane);

    const float s_ud = scal[0], s_ur = scal[1], s_ru = scal[2],
                s_rd = scal[3], s_du = scal[4], s_dr = scal[5];

    bf16* orow = obuf + b * 3072;
    const int j0 = tid * 4;
    const float uu[4] = {u0, u1, u2, u3};
    const float dd[4] = {d0, d1, d2, d3};
    const float rr[4] = {zn.x, zn.y, zn.z, zn.w};
#pragma unroll
    for (int i = 0; i < 4; ++i) {
        const float O1 = sigm(s_ud * uu[i] * du) + sigm(s_ur * uu[i] * ru);
        const float O2 = sigm(s_ru * rr[i] * ru) + sigm(s_rd * rr[i] * dr);
        const float O3 = sigm(s_du * dd[i] * du) + sigm(s_dr * dd[i] * dr);
        orow[j0 + i]            = __float2bfloat16(O1);
        orow[U + j0 + i]        = __float2bfloat16(O2);
        orow[2 * U + j0 + i]    = __float2bfloat16(O3);
    }
}

// ---------------------------------------------------------------------------
// f = sigmoid(O @ agg); c' = f*c + (1-f)*tanh(z4); h' = z3*tanh(c'); emit out.
// grid 32 blocks (n-tile 32 of 1024), 4 waves k-split over 96 ksteps.
__global__ __launch_bounds__(256) void k_fgate(const bf16* __restrict__ obuf,
                                               const bf16* __restrict__ aggt,
                                               const float* __restrict__ z,
                                               float* __restrict__ c32,
                                               bf16* __restrict__ abuf,
                                               float* __restrict__ out, int t) {
    __shared__ float lacc[4][8][64][4];
    const int tid = threadIdx.x;
    const int w = tid >> 6, lane = tid & 63;
    const int n0 = blockIdx.x * 32;
    const int q = lane >> 4, ml = lane & 15;
    const int nA = n0 + ml, nB = n0 + 16 + ml;

    f32x4 acc[8];
#pragma unroll
    for (int i = 0; i < 8; ++i) acc[i] = (f32x4){0.f, 0.f, 0.f, 0.f};

    for (int i = 0; i < 24; ++i) {
        const int p = i * 4 + w;
        const int kb = p * 32 + q * 8;
        bf16x8 a[4], bb[2];
#pragma unroll
        for (int mi = 0; mi < 4; ++mi)
            a[mi] = *(const bf16x8*)(obuf + (mi * 16 + ml) * 3072 + kb);
        bb[0] = *(const bf16x8*)(aggt + nA * 3072 + kb);
        bb[1] = *(const bf16x8*)(aggt + nB * 3072 + kb);
#pragma unroll
        for (int ni = 0; ni < 2; ++ni)
#pragma unroll
            for (int mi = 0; mi < 4; ++mi)
                acc[mi * 2 + ni] = __builtin_amdgcn_mfma_f32_16x16x32_bf16(
                    a[mi], bb[ni], acc[mi * 2 + ni], 0, 0, 0);
    }

#pragma unroll
    for (int tile = 0; tile < 8; ++tile)
        *(f32x4*)&lacc[w][tile][lane][0] = acc[tile];
    __syncthreads();

    for (int idx = tid; idx < 2048; idx += 256) {
        const int tile = idx >> 8, rem = idx & 255, ln = rem >> 2, r = rem & 3;
        const float v = lacc[0][tile][ln][r] + lacc[1][tile][ln][r]
                      + lacc[2][tile][ln][r] + lacc[3][tile][ln][r];
        const int mi = tile >> 1, ni = tile & 1;
        const int row = mi * 16 + (ln >> 4) * 4 + r;        // batch index
        const int col = n0 + ni * 16 + (ln & 15);           // u index
        const float f = sigm(v);
        const float cold = c32[row * U + col];
        const float z3 = z[row * N5 + 3 * U + col];
        const float z4 = z[row * N5 + 4 * U + col];
        const float cn = f * cold + (1.f - f) * tanhf(z4);
        const float hn = z3 * tanhf(cn);
        c32[row * U + col] = cn;
        const bf16 ch = __float2bfloat16(cn);
        const bf16 cl = __float2bfloat16(cn - __bfloat162float(ch));
        const bf16 hh = __float2bfloat16(hn);
        const bf16 hl = __float2bfloat16(hn - __bfloat162float(hh));
        abuf[0 * 65536 + row * U + col] = hh;
        abuf[1 * 65536 + row * U + col] = hl;
        abuf[2 * 65536 + row * U + col] = ch;
        abuf[3 * 65536 + row * U + col] = cl;
        out[(row * TSTEPS + t) * U + col] = hn;
    }
}

// ---------------------------------------------------------------------------
extern "C" void kernel_launch(void* const* d_in, const int* in_sizes, int n_in,
                              void* d_out, int out_size, void* d_ws, size_t ws_size,
                              hipStream_t stream) {
    (void)in_sizes; (void)n_in; (void)out_size; (void)ws_size;
    const float* x    = (const float*)d_in[0];
    const float* Wk   = (const float*)d_in[1];   // (256,5120)
    const float* Wr   = (const float*)d_in[2];   // (1024,5120)
    const float* Wc   = (const float*)d_in[3];   // (1024,5120)
    const float* bias = (const float*)d_in[4];   // (5120)
    const float* agg  = (const float*)d_in[5];   // (3072,1024)

    char* ws = (char*)d_ws;
    bf16*  wrct = (bf16*)(ws + OFF_WRC);
    bf16*  kt   = (bf16*)(ws + OFF_KT);
    bf16*  aggt = (bf16*)(ws + OFF_AGGT);
    bf16*  xbf  = (bf16*)(ws + OFF_XBF);
    float* zbuf = (float*)(ws + OFF_Z);
    bf16*  abuf = (bf16*)(ws + OFF_ABUF);
    float* c32  = (float*)(ws + OFF_C32);
    bf16*  obuf = (bf16*)(ws + OFF_OBUF);
    float* scal = (float*)(ws + OFF_SCAL);
    float* out  = (float*)d_out;

    hipMemsetAsync(abuf, 0, 4 * 65536 * sizeof(bf16), stream);
    hipMemsetAsync(c32, 0, BATCH * U * sizeof(float), stream);

    // one-time conversions / transposes
    k_xconv<<<(BATCH * TSTEPS * DIM / 4 + 255) / 256, 256, 0, stream>>>(x, xbf, BATCH * TSTEPS * DIM / 4);
    k_transpose<<<dim3(5120 / 64, 1024 / 64), 256, 0, stream>>>(Wr, wrct, 5120, 2048, 0);
    k_transpose<<<dim3(5120 / 64, 1024 / 64), 256, 0, stream>>>(Wc, wrct, 5120, 2048, 1024);
    k_transpose<<<dim3(5120 / 64, 256 / 64),  256, 0, stream>>>(Wk, kt,   5120, 256, 0);
    k_transpose<<<dim3(1024 / 64, 3072 / 64), 256, 0, stream>>>(agg, aggt, 1024, 3072, 0);

    AttPtrs ap;
    for (int i = 0; i < 12; ++i) ap.p[i] = (const float*)d_in[6 + i];
    k_scal<<<1, 256, 0, stream>>>(ap, scal);

    for (int t = 0; t < TSTEPS; ++t) {
        k_zgemm<<<160, 256, 0, stream>>>(xbf, kt, wrct, abuf, bias, zbuf, t);
        k_gates<<<64, 256, 0, stream>>>(zbuf, scal, obuf);
        k_fgate<<<32, 256, 0, stream>>>(obuf, aggt, zbuf, c32, abuf, out, t);
    }
}